// Round 2
// baseline (253.386 us; speedup 1.0000x reference)
//
#include <hip/hip_runtime.h>
#include <hip/hip_bf16.h>

#define LL 768
#define TOPK 128

// workspace layout (floats)
#define WS_SEQ  0                       // 768*256
#define WS_NODE (WS_SEQ + LL*256)       // 768*32
#define WS_NBR  (WS_NODE + LL*32)       // 768*128 ints
#define WS_SOUT (WS_NBR + LL*TOPK)      // 768*16

#define FMA_ROW32(ACC, XVAL, WPTR) do {                                   \
    const float _x = (XVAL);                                              \
    const float* __restrict__ _w = (WPTR);                                \
    _Pragma("unroll")                                                     \
    for (int _c = 0; _c < 32; ++_c) ACC[_c] = fmaf(_x, _w[_c], ACC[_c]);  \
  } while (0)

__device__ __forceinline__ float block_sum_256(float v, float* red, int t) {
#pragma unroll
  for (int o = 32; o > 0; o >>= 1) v += __shfl_xor(v, o, 64);
  __syncthreads();
  if ((t & 63) == 0) red[t >> 6] = v;
  __syncthreads();
  return red[0] + red[1] + red[2] + red[3];
}

// ---------------- Kernel A: seq LN, state LN, node MLP + LN ----------------
__global__ __launch_bounds__(256) void kernA(
    const float* __restrict__ msa, const float* __restrict__ state,
    const float* __restrict__ W_en, const float* __restrict__ b_en,
    const float* __restrict__ Wn1, const float* __restrict__ bn1,
    const float* __restrict__ Wn2, const float* __restrict__ bn2,
    float* __restrict__ seq_ln, float* __restrict__ nodeo)
{
  const int i = blockIdx.x, t = threadIdx.x;
  __shared__ float x[256];
  __shared__ float red[4];
  __shared__ float sn[16], n0[32], tn[32], hh[64], n1v[32];

  float v = msa[i*256 + t];
  float mean = block_sum_256(v, red, t) * (1.f/256.f);
  float d = v - mean;
  float var = block_sum_256(d*d, red, t) * (1.f/256.f);
  float xn = d / sqrtf(var + 1e-5f);
  x[t] = xn;
  seq_ln[i*256 + t] = xn;

  if (t < 16) {
    float m2 = 0.f;
    for (int k = 0; k < 16; ++k) m2 += state[i*16 + k];
    m2 *= (1.f/16.f);
    float v2 = 0.f;
    for (int k = 0; k < 16; ++k) { float dd = state[i*16 + k] - m2; v2 += dd*dd; }
    v2 *= (1.f/16.f);
    sn[t] = (state[i*16 + t] - m2) / sqrtf(v2 + 1e-5f);
  }
  __syncthreads();

  if (t < 32) {
    float a = b_en[t];
    for (int k = 0; k < 256; ++k) a = fmaf(x[k], W_en[k*32 + t], a);
    for (int k = 0; k < 16; ++k)  a = fmaf(sn[k], W_en[(256+k)*32 + t], a);
    n0[t] = a;
  }
  __syncthreads();
  if (t < 32) {
    float m = 0.f;
    for (int k = 0; k < 32; ++k) m += n0[k];
    m *= (1.f/32.f);
    float vv = 0.f;
    for (int k = 0; k < 32; ++k) { float dd = n0[k] - m; vv += dd*dd; }
    vv *= (1.f/32.f);
    tn[t] = (n0[t] - m) / sqrtf(vv + 1e-5f);
  }
  __syncthreads();
  if (t < 64) {
    float a = bn1[t];
    for (int k = 0; k < 32; ++k) a = fmaf(tn[k], Wn1[k*64 + t], a);
    hh[t] = fmaxf(a, 0.f);
  }
  __syncthreads();
  if (t < 32) {
    float a = n0[t] + bn2[t];
    for (int k = 0; k < 64; ++k) a = fmaf(hh[k], Wn2[k*32 + t], a);
    n1v[t] = a;
  }
  __syncthreads();
  if (t < 32) {
    float m = 0.f;
    for (int k = 0; k < 32; ++k) m += n1v[k];
    m *= (1.f/32.f);
    float vv = 0.f;
    for (int k = 0; k < 32; ++k) { float dd = n1v[k] - m; vv += dd*dd; }
    vv *= (1.f/32.f);
    nodeo[i*32 + t] = (n1v[t] - m) / sqrtf(vv + 1e-5f);
  }
}

// ---------------- Kernel B: top-128 nearest by D, bitonic (D_bits, j) -------
__global__ __launch_bounds__(256) void kernB(const float* __restrict__ xyz,
                                             int* __restrict__ nbr)
{
  const int i = blockIdx.x, t = threadIdx.x;
  __shared__ unsigned long long keys[1024];
  const float cix = xyz[i*9+3], ciy = xyz[i*9+4], ciz = xyz[i*9+5];

  for (int j = t; j < 1024; j += 256) {
    unsigned long long kk = ~0ull;
    if (j < LL) {
      float dx = __fadd_rn(cix, -xyz[j*9+3]);
      float dy = __fadd_rn(ciy, -xyz[j*9+4]);
      float dz = __fadd_rn(ciz, -xyz[j*9+5]);
      float Dv = sqrtf(__fadd_rn(__fadd_rn(__fadd_rn(__fmul_rn(dx,dx),
                         __fmul_rn(dy,dy)), __fmul_rn(dz,dz)), 1e-8f));
      kk = (((unsigned long long)__float_as_uint(Dv)) << 32) | (unsigned)j;
    }
    keys[j] = kk;
  }
  for (int size = 2; size <= 1024; size <<= 1) {
    for (int stride = size >> 1; stride > 0; stride >>= 1) {
      __syncthreads();
      for (int p = t; p < 512; p += 256) {
        int lo = 2*p - (p & (stride - 1));
        int hi = lo + stride;
        bool up = ((lo & size) == 0);
        unsigned long long a = keys[lo], b = keys[hi];
        if ((a > b) == up) { keys[lo] = b; keys[hi] = a; }
      }
    }
  }
  __syncthreads();
  if (t < TOPK) nbr[i*TOPK + t] = (int)(keys[t] & 0xffffffffu);
}

// ---------------- Kernel C: edge+message pipeline for selected neighbors ----
__global__ __launch_bounds__(128, 2) void kernC(
    const float* __restrict__ pair, const float* __restrict__ xyz,
    const int* __restrict__ idx, const unsigned char* __restrict__ rmask,
    const float* __restrict__ W_ee, const float* __restrict__ b_ee,
    const float* __restrict__ We1, const float* __restrict__ be1,
    const float* __restrict__ We2, const float* __restrict__ be2,
    const float* __restrict__ Wm1, const float* __restrict__ bm1,
    const float* __restrict__ Wm2, const float* __restrict__ bm2,
    const float* __restrict__ Wl0, const float* __restrict__ bl0,
    const float* __restrict__ node, const int* __restrict__ nbr,
    float* __restrict__ soutf, float* __restrict__ out)
{
  const int i = blockIdx.x;
  const int t = threadIdx.x;
  __shared__ float scr[128 * 97];   // per-thread row, stride 97 (bank-safe)
  __shared__ float ni[32];
  __shared__ float red[2][44];
  __shared__ float fin[44];

  if (t < 32) ni[t] = node[i*32 + t];
  __syncthreads();

  float* myscr = scr + t * 97;
  const int j = nbr[i*TOPK + t];
  const float cix = xyz[i*9+3], ciy = xyz[i*9+4], ciz = xyz[i*9+5];
  const float cjx = xyz[j*9+3], cjy = xyz[j*9+4], cjz = xyz[j*9+5];
  const float dx = __fadd_rn(cix, -cjx), dy = __fadd_rn(ciy, -cjy), dz = __fadd_rn(ciz, -cjz);
  const float Dv = sqrtf(__fadd_rn(__fadd_rn(__fadd_rn(__fmul_rn(dx,dx),
                      __fmul_rn(dy,dy)), __fmul_rn(dz,dz)), 1e-8f));

  const float* prow = pair + ((size_t)i*LL + j) * 128;
  // pass A: pair-row LN stats
  float s = 0.f, ss = 0.f;
  for (int k4 = 0; k4 < 32; ++k4) {
    float4 v = ((const float4*)prow)[k4];
    s  += v.x + v.y + v.z + v.w;
    ss += v.x*v.x + v.y*v.y + v.z*v.z + v.w*v.w;
  }
  const float pm  = s * (1.f/128.f);
  const float pvv = ss * (1.f/128.f) - pm*pm;
  const float prs = 1.f / sqrtf(pvv + 1e-5f);

  // edge0 = [pair_n | rbf | seqsep] @ W_ee + b_ee
  float acc[32];
#pragma unroll
  for (int c = 0; c < 32; ++c) acc[c] = b_ee[c];
  for (int k = 0; k < 128; ++k)
    FMA_ROW32(acc, (prow[k] - pm) * prs, W_ee + k*32);
  for (int k = 0; k < 64; ++k) {
    float mu = 2.f + (float)k * (20.f/63.f);
    float u  = (Dv - mu) / 0.3125f;
    FMA_ROW32(acc, expf(-(u*u)), W_ee + (128+k)*32);
  }
  {
    float offv = (float)(idx[j] - idx[i]);
    float sg = (offv > 0.f) ? 1.f : ((offv < 0.f) ? -1.f : 0.f);
    FMA_ROW32(acc, sg * logf(fabsf(offv) + 1.f), W_ee + 192*32);
  }

  // LN(edge0) -> myscr[0..31]
  {
    float m = 0.f;
#pragma unroll
    for (int c = 0; c < 32; ++c) m += acc[c];
    m *= (1.f/32.f);
    float vv = 0.f;
#pragma unroll
    for (int c = 0; c < 32; ++c) { float dd = acc[c] - m; vv += dd*dd; }
    vv *= (1.f/32.f);
    float rs = 1.f / sqrtf(vv + 1e-5f);
#pragma unroll
    for (int c = 0; c < 32; ++c) myscr[c] = (acc[c] - m) * rs;
  }
  // h = relu(t @ We1 + be1) -> myscr[32..95]
  {
    float h[64];
#pragma unroll
    for (int c = 0; c < 64; ++c) h[c] = be1[c];
    for (int k = 0; k < 32; ++k) {
      float xv = myscr[k];
#pragma unroll
      for (int c = 0; c < 64; ++c) h[c] = fmaf(xv, We1[k*64 + c], h[c]);
    }
#pragma unroll
    for (int c = 0; c < 64; ++c) myscr[32 + c] = fmaxf(h[c], 0.f);
  }
  // e2 = edge0 + h @ We2 + be2
#pragma unroll
  for (int c = 0; c < 32; ++c) acc[c] += be2[c];
  for (int k = 0; k < 64; ++k) {
    float xv = myscr[32 + k];
#pragma unroll
    for (int c = 0; c < 32; ++c) acc[c] = fmaf(xv, We2[k*32 + c], acc[c]);
  }
  // LN(e2) -> edge into myscr[0..31]
  {
    float m = 0.f;
#pragma unroll
    for (int c = 0; c < 32; ++c) m += acc[c];
    m *= (1.f/32.f);
    float vv = 0.f;
#pragma unroll
    for (int c = 0; c < 32; ++c) { float dd = acc[c] - m; vv += dd*dd; }
    vv *= (1.f/32.f);
    float rs = 1.f / sqrtf(vv + 1e-5f);
#pragma unroll
    for (int c = 0; c < 32; ++c) myscr[c] = (acc[c] - m) * rs;
  }
  // h_j -> myscr[32..63]
#pragma unroll
  for (int c = 0; c < 32; ++c) myscr[32 + c] = node[j*32 + c];

  // message MLP: m1 = relu([h_i,h_j,edge]@Wm1+bm1); m2 = m1@Wm2+bm2
  float m2[40];
  {
    float m1[64];
#pragma unroll
    for (int c = 0; c < 64; ++c) m1[c] = bm1[c];
    for (int k = 0; k < 32; ++k) {
      float xv = ni[k];
#pragma unroll
      for (int c = 0; c < 64; ++c) m1[c] = fmaf(xv, Wm1[k*64 + c], m1[c]);
    }
    for (int k = 0; k < 32; ++k) {
      float xv = myscr[32 + k];
#pragma unroll
      for (int c = 0; c < 64; ++c) m1[c] = fmaf(xv, Wm1[(32+k)*64 + c], m1[c]);
    }
    for (int k = 0; k < 32; ++k) {
      float xv = myscr[k];
#pragma unroll
      for (int c = 0; c < 64; ++c) m1[c] = fmaf(xv, Wm1[(64+k)*64 + c], m1[c]);
    }
#pragma unroll
    for (int c = 0; c < 64; ++c) myscr[32 + c] = fmaxf(m1[c], 0.f);
  }
#pragma unroll
  for (int o = 0; o < 40; ++o) m2[o] = bm2[o];
  for (int k = 0; k < 64; ++k) {
    float xv = myscr[32 + k];
#pragma unroll
    for (int o = 0; o < 40; ++o) m2[o] = fmaf(xv, Wm2[k*40 + o], m2[o]);
  }

  // per-thread contributions -> block reduce (deterministic shuffle tree)
  const float rx = cjx - cix, ry = cjy - ciy, rz = cjz - ciz;
  float contrib[44];
#pragma unroll
  for (int q = 0; q < 32; ++q) contrib[q] = m2[q];
  contrib[32] = m2[32]*rx; contrib[33] = m2[32]*ry; contrib[34] = m2[32]*rz;
  contrib[35] = m2[33]*rx; contrib[36] = m2[33]*ry; contrib[37] = m2[33]*rz;
#pragma unroll
  for (int q = 0; q < 6; ++q) contrib[38 + q] = m2[34 + q];

#pragma unroll
  for (int q = 0; q < 44; ++q) {
    float v = contrib[q];
#pragma unroll
    for (int o = 32; o > 0; o >>= 1) v += __shfl_xor(v, o, 64);
    if ((t & 63) == 0) red[t >> 6][q] = v;
  }
  __syncthreads();
  if (t < 44) fin[t] = red[0][t] + red[1][t];
  __syncthreads();

  if (t < 16) {  // state_out = [node_i, m_l0] @ Wl0 + bl0
    float a = bl0[t];
#pragma unroll
    for (int k = 0; k < 32; ++k) a = fmaf(ni[k], Wl0[k*16 + t], a);
#pragma unroll
    for (int k = 0; k < 32; ++k) a = fmaf(fin[k] * (1.f/128.f), Wl0[(32+k)*16 + t], a);
    soutf[i*16 + t] = a;
    out[LL*9 + i*16 + t] = a;
  }
  if (t == 0) {  // frame update
    float ve[6], wa[6];
#pragma unroll
    for (int q = 0; q < 6; ++q) ve[q] = fin[32 + q] * (1.f/128.f);
#pragma unroll
    for (int q = 0; q < 6; ++q) wa[q] = fin[38 + q] * (1.f/128.f);
    float l1[9];
#pragma unroll
    for (int a = 0; a < 3; ++a)
#pragma unroll
      for (int d = 0; d < 3; ++d) l1[a*3 + d] = xyz[i*9 + a*3 + d] - xyz[i*9 + 3 + d];
    float T[3], Rv[3];
#pragma unroll
    for (int d = 0; d < 3; ++d) {
      float va0 = wa[0]*l1[d] + wa[1]*l1[3 + d] + wa[2]*l1[6 + d];
      float va1 = wa[3]*l1[d] + wa[4]*l1[3 + d] + wa[5]*l1[6 + d];
      T[d]  = (ve[d] + va0) / 10.f;
      Rv[d] = (ve[3 + d] + va1) / 100.f;
    }
    float qn = sqrtf(1.f + Rv[0]*Rv[0] + Rv[1]*Rv[1] + Rv[2]*Rv[2]);
    float qA = 1.f/qn, qB = Rv[0]/qn, qC = Rv[1]/qn, qD = Rv[2]/qn;
    float Rm[9];
    Rm[0] = qA*qA + qB*qB - qC*qC - qD*qD;
    Rm[1] = 2.f*qB*qC - 2.f*qA*qD;
    Rm[2] = 2.f*qB*qD + 2.f*qA*qC;
    Rm[3] = 2.f*qB*qC + 2.f*qA*qD;
    Rm[4] = qA*qA - qB*qB + qC*qC - qD*qD;
    Rm[5] = 2.f*qC*qD - 2.f*qA*qB;
    Rm[6] = 2.f*qB*qD - 2.f*qA*qC;
    Rm[7] = 2.f*qC*qD + 2.f*qA*qB;
    Rm[8] = qA*qA - qB*qB - qC*qC + qD*qD;
    if (rmask[i]) {
      Rm[0] = 1.f; Rm[1] = 0.f; Rm[2] = 0.f;
      Rm[3] = 0.f; Rm[4] = 1.f; Rm[5] = 0.f;
      Rm[6] = 0.f; Rm[7] = 0.f; Rm[8] = 1.f;
    }
#pragma unroll
    for (int a = 0; a < 3; ++a)
#pragma unroll
      for (int di = 0; di < 3; ++di) {
        float xn = Rm[di*3+0]*l1[a*3+0] + Rm[di*3+1]*l1[a*3+1] + Rm[di*3+2]*l1[a*3+2]
                 + xyz[i*9 + 3 + di] + T[di];
        out[i*9 + a*3 + di] = xn;
      }
  }
}

// ---------------- Kernel D: si MLP stack -> alpha ---------------------------
__global__ __launch_bounds__(128) void kernD(
    const float* __restrict__ seq_ln, const float* __restrict__ st_out,
    const float* __restrict__ Ws0, const float* __restrict__ bs0,
    const float* __restrict__ Wsi, const float* __restrict__ bsi,
    const float* __restrict__ Wp1, const float* __restrict__ bp1,
    const float* __restrict__ Wp2, const float* __restrict__ bp2,
    const float* __restrict__ Wp3, const float* __restrict__ bp3,
    const float* __restrict__ Wp4, const float* __restrict__ bp4,
    const float* __restrict__ Wout, const float* __restrict__ bout,
    float* __restrict__ out)
{
  const int i = blockIdx.x, t = threadIdx.x;
  __shared__ float x0[256], stn[16], ra[128], ga[128], rb[128], gb[128], rc[128];
  x0[t]       = seq_ln[i*256 + t];
  x0[128 + t] = seq_ln[i*256 + 128 + t];
  if (t < 16) {
    float m = 0.f;
    for (int k = 0; k < 16; ++k) m += st_out[i*16 + k];
    m *= (1.f/16.f);
    float v = 0.f;
    for (int k = 0; k < 16; ++k) { float dd = st_out[i*16 + k] - m; v += dd*dd; }
    v *= (1.f/16.f);
    stn[t] = (st_out[i*16 + t] - m) / sqrtf(v + 1e-5f);
  }
  __syncthreads();

  float si = bs0[t] + bsi[t];
  for (int k = 0; k < 256; ++k) si = fmaf(x0[k], Ws0[k*128 + t], si);
  for (int k = 0; k < 16; ++k)  si = fmaf(stn[k], Wsi[k*128 + t], si);
  ra[t] = fmaxf(si, 0.f);
  __syncthreads();
  float h = bp1[t];
  for (int k = 0; k < 128; ++k) h = fmaf(ra[k], Wp1[k*128 + t], h);
  ga[t] = fmaxf(h, 0.f);
  __syncthreads();
  float d2 = bp2[t];
  for (int k = 0; k < 128; ++k) d2 = fmaf(ga[k], Wp2[k*128 + t], d2);
  si += d2;
  rb[t] = fmaxf(si, 0.f);
  __syncthreads();
  float h2 = bp3[t];
  for (int k = 0; k < 128; ++k) h2 = fmaf(rb[k], Wp3[k*128 + t], h2);
  gb[t] = fmaxf(h2, 0.f);
  __syncthreads();
  float d4 = bp4[t];
  for (int k = 0; k < 128; ++k) d4 = fmaf(gb[k], Wp4[k*128 + t], d4);
  si += d4;
  rc[t] = fmaxf(si, 0.f);
  __syncthreads();
  if (t < 20) {
    float a = bout[t];
    for (int k = 0; k < 128; ++k) a = fmaf(rc[k], Wout[k*20 + t], a);
    out[19200 + i*20 + t] = a;
  }
}

extern "C" void kernel_launch(void* const* d_in, const int* in_sizes, int n_in,
                              void* d_out, int out_size, void* d_ws, size_t ws_size,
                              hipStream_t stream)
{
  (void)in_sizes; (void)n_in; (void)out_size; (void)ws_size;
  const float* msa   = (const float*)d_in[0];
  const float* pair  = (const float*)d_in[1];
  const float* xyz   = (const float*)d_in[2];
  const float* state = (const float*)d_in[3];
  const int*   idx   = (const int*)d_in[4];
  const unsigned char* rmask = (const unsigned char*)d_in[5];
  const float* W_en = (const float*)d_in[6];
  const float* b_en = (const float*)d_in[7];
  const float* Wn1  = (const float*)d_in[8];
  const float* bn1  = (const float*)d_in[9];
  const float* Wn2  = (const float*)d_in[10];
  const float* bn2  = (const float*)d_in[11];
  const float* W_ee = (const float*)d_in[12];
  const float* b_ee = (const float*)d_in[13];
  const float* We1  = (const float*)d_in[14];
  const float* be1  = (const float*)d_in[15];
  const float* We2  = (const float*)d_in[16];
  const float* be2  = (const float*)d_in[17];
  const float* Wm1  = (const float*)d_in[18];
  const float* bm1  = (const float*)d_in[19];
  const float* Wm2  = (const float*)d_in[20];
  const float* bm2  = (const float*)d_in[21];
  const float* Wl0  = (const float*)d_in[22];
  const float* bl0  = (const float*)d_in[23];
  const float* Ws0  = (const float*)d_in[24];
  const float* bs0  = (const float*)d_in[25];
  const float* Wsi  = (const float*)d_in[26];
  const float* bsi  = (const float*)d_in[27];
  const float* Wp1  = (const float*)d_in[28];
  const float* bp1  = (const float*)d_in[29];
  const float* Wp2  = (const float*)d_in[30];
  const float* bp2  = (const float*)d_in[31];
  const float* Wp3  = (const float*)d_in[32];
  const float* bp3  = (const float*)d_in[33];
  const float* Wp4  = (const float*)d_in[34];
  const float* bp4  = (const float*)d_in[35];
  const float* Wout = (const float*)d_in[36];
  const float* bout = (const float*)d_in[37];

  float* wsf    = (float*)d_ws;
  float* seq_ln = wsf + WS_SEQ;
  float* nodev  = wsf + WS_NODE;
  int*   nbr    = (int*)(wsf + WS_NBR);
  float* soutf  = wsf + WS_SOUT;
  float* out = (float*)d_out;

  kernA<<<LL, 256, 0, stream>>>(msa, state, W_en, b_en, Wn1, bn1, Wn2, bn2, seq_ln, nodev);
  kernB<<<LL, 256, 0, stream>>>(xyz, nbr);
  kernC<<<LL, 128, 0, stream>>>(pair, xyz, idx, rmask, W_ee, b_ee, We1, be1, We2, be2,
                                Wm1, bm1, Wm2, bm2, Wl0, bl0, nodev, nbr, soutf, out);
  kernD<<<LL, 128, 0, stream>>>(seq_ln, soutf, Ws0, bs0, Wsi, bsi, Wp1, bp1, Wp2, bp2,
                                Wp3, bp3, Wp4, bp4, Wout, bout, out);
}